// Round 14
// baseline (162.445 us; speedup 1.0000x reference)
//
#include <hip/hip_runtime.h>

#define N_NODES 50000
#define N_EDGES 800000
#define N_GRAPHS 128
#define IN_DIM 256
#define OUT_DIM 128
#define NEG_SLOPE 0.01f

#define RCHUNK 64
#define NB_SCAN ((N_NODES + 255) / 256)   // 196 blocks for the scan

#define NSLICE 4
#define SLICE 12544                        // 4*12544 = 50176 >= N_NODES
#define NTOT (NSLICE * SLICE)              // 50176
#define NCHUNK 64
#define NE4 (N_EDGES / 4)                  // 200000 int4 quads
#define QPC (NE4 / NCHUNK)                 // 3125 quads per chunk

typedef __attribute__((ext_vector_type(8))) short bf16x8;
typedef __attribute__((ext_vector_type(4))) float f32x4;
typedef unsigned short ushort_t;
typedef unsigned int uint_t;

__device__ inline ushort_t f2b(float f) {          // fp32 -> bf16 bits, RNE
    union { float f; unsigned u; } c{f};
    unsigned r = c.u + 0x7FFFu + ((c.u >> 16) & 1u);
    return (ushort_t)(r >> 16);
}
__device__ inline float b2f(ushort_t u) {          // bf16 bits -> fp32
    union { unsigned u; float f; } c{(unsigned)u << 16};
    return c.f;
}
__device__ inline float blo(uint_t v) {            // low bf16 of packed pair
    union { unsigned u; float f; } c{v << 16};
    return c.f;
}
__device__ inline float bhi(uint_t v) {            // high bf16 of packed pair
    union { unsigned u; float f; } c{v & 0xFFFF0000u};
    return c.f;
}

// ------- degree histograms: packed-u16 LDS bins (25KB), zero global atomics -------
// bins32[i] holds counts for nodes {2i (lo16), 2i+1 (hi16)}; counts <= 12500 so
// no carry across the halves. Matches rep's packed-u16 pair format directly.
__global__ __launch_bounds__(256) void deg_kernel(const int4* __restrict__ src4,
                                                  const int4* __restrict__ dst4,
                                                  ushort_t* __restrict__ rep) {
    __shared__ uint_t bins[SLICE / 2];   // 25KB -> 6 blocks/CU
    int b     = blockIdx.x;
    int hist  = b >> 8;                  // 0: src (out-deg), 1: dst (in-deg)
    int rem   = b & 255;
    int slice = rem >> 6;
    int chunk = rem & 63;
    const int4* ea = hist ? dst4 : src4;
    int lo = slice * SLICE;

    for (int i = threadIdx.x; i < SLICE / 2; i += 256) bins[i] = 0;
    __syncthreads();

    int q0 = chunk * QPC;
    int q1 = q0 + QPC;
    for (int q = q0 + threadIdx.x; q < q1; q += 256) {
        int4 e = ea[q];
        unsigned a0 = (unsigned)(e.x - lo);
        if (a0 < SLICE) atomicAdd(&bins[a0 >> 1], 1u << ((a0 & 1) << 4));
        unsigned a1 = (unsigned)(e.y - lo);
        if (a1 < SLICE) atomicAdd(&bins[a1 >> 1], 1u << ((a1 & 1) << 4));
        unsigned a2 = (unsigned)(e.z - lo);
        if (a2 < SLICE) atomicAdd(&bins[a2 >> 1], 1u << ((a2 & 1) << 4));
        unsigned a3 = (unsigned)(e.w - lo);
        if (a3 < SLICE) atomicAdd(&bins[a3 >> 1], 1u << ((a3 & 1) << 4));
    }
    __syncthreads();

    uint_t* rp32 = (uint_t*)(rep + (size_t)(hist * NCHUNK + chunk) * NTOT + lo);
    for (int i = threadIdx.x; i < SLICE / 2; i += 256)
        rp32[i] = bins[i];
}

// ---- reduce replicas -> norms + deg_in; in-place chunk-prefix scan; fused block sums ----
__global__ __launch_bounds__(256) void norm_kernel(ushort_t* __restrict__ rep,
                                                   float* __restrict__ out_norm,
                                                   float* __restrict__ in_norm,
                                                   int* __restrict__ deg_in_tot,
                                                   int* __restrict__ bsum) {
    __shared__ int red[256];
    int t = threadIdx.x;
    int i = blockIdx.x * 256 + t;
    int si_keep = 0;
    if (i < N_NODES) {
        int so = 0;
#pragma unroll
        for (int c = 0; c < NCHUNK; ++c) so += rep[(size_t)c * NTOT + i];
        int si = 0;
#pragma unroll
        for (int c = 0; c < NCHUNK; ++c) {       // exclusive scan, in place
            size_t off = (size_t)(NCHUNK + c) * NTOT + i;
            int v = rep[off];
            rep[off] = (ushort_t)si;
            si += v;
        }
        deg_in_tot[i] = si;
        si_keep = si;
        int dq = so > 1 ? so : 1;
        int di = si > 1 ? si : 1;
        out_norm[i] = rsqrtf((float)dq);
        in_norm[i]  = rsqrtf((float)di);
    }
    red[t] = si_keep;
    __syncthreads();
    for (int off = 128; off > 0; off >>= 1) {
        if (t < off) red[t] += red[t + off];
        __syncthreads();
    }
    if (t == 0) bsum[blockIdx.x] = red[0];
}

// ---- merged fill + wc: blocks 0..195 build row_ofs; blocks 196..452 fold weights ----
// (independent work; merged to save a launch)
__global__ __launch_bounds__(256) void fillwc_kernel(const int* __restrict__ deg_in,
                                                     const int* __restrict__ bsum,
                                                     int* __restrict__ row_ofs,
                                                     const float* __restrict__ w_red,
                                                     const float* __restrict__ b_red,
                                                     const float* __restrict__ w2,
                                                     ushort_t* __restrict__ Wcs,
                                                     float* __restrict__ bc,
                                                     float* __restrict__ g) {
    int t   = threadIdx.x;
    int bid = blockIdx.x;

    if (bid < NB_SCAN) {
        // ---------- fill part ----------
        __shared__ int sh[256];
        // phase A: scan block sums
        int v = (t < NB_SCAN) ? bsum[t] : 0;
        sh[t] = v;
        __syncthreads();
        for (int off = 1; off < 256; off <<= 1) {
            int a = sh[t];
            int b = (t >= off) ? sh[t - off] : 0;
            __syncthreads();
            sh[t] = a + b;
            __syncthreads();
        }
        int bofs  = sh[bid] - bsum[bid];          // exclusive prefix of this block
        int total = sh[NB_SCAN - 1];
        __syncthreads();

        // phase B: block-local scan of degrees
        int idx = bid * 256 + t;
        int dv  = (idx < N_NODES) ? deg_in[idx] : 0;
        sh[t] = dv;
        __syncthreads();
        for (int off = 1; off < 256; off <<= 1) {
            int a = sh[t];
            int b = (t >= off) ? sh[t - off] : 0;
            __syncthreads();
            sh[t] = a + b;
            __syncthreads();
        }
        if (idx < N_NODES) row_ofs[idx] = bofs + sh[t] - dv;
        if (bid == 0 && t == 0) row_ofs[N_NODES] = total;   // = N_EDGES
    } else if (t < OUT_DIM) {
        // ---------- wc part: Wcs[n][k] = bf16(sum_c w_red[k][c] w2[c][n]) ----------
        int i = bid - NB_SCAN;   // k: 0..256 (i==IN_DIM computes bc)
        int j = t;               // n: 0..127
        if (i < N_GRAPHS) g[i * OUT_DIM + j] = 0.f;   // zero g (replaces memset)
        const float* vin = (i < IN_DIM) ? (w_red + (size_t)i * OUT_DIM) : b_red;
        float s = 0.f;
        for (int k = 0; k < OUT_DIM; ++k) s = fmaf(vin[k], w2[k * OUT_DIM + j], s);
        if (i < IN_DIM) Wcs[(size_t)j * IN_DIM + i] = f2b(s);   // transposed, bf16
        else            bc[j] = s;
    }
}

// ---------------- chunked bucket fill: LDS cursors, zero global atomics ----------------
__global__ __launch_bounds__(256) void build_kernel(const int4* __restrict__ src4,
                                                    const int4* __restrict__ dst4,
                                                    const int* __restrict__ row_ofs,
                                                    const ushort_t* __restrict__ rep,
                                                    int* __restrict__ esrc) {
    __shared__ int cur[SLICE];
    int b     = blockIdx.x;
    int slice = b >> 6;
    int chunk = b & 63;
    int lo    = slice * SLICE;
    const ushort_t* rel = rep + (size_t)(NCHUNK + chunk) * NTOT + lo;

    for (int i = threadIdx.x; i < SLICE; i += 256) {
        int n = lo + i;
        int r = (n < N_NODES) ? row_ofs[n] : 0;
        cur[i] = r + (int)rel[i];
    }
    __syncthreads();

    int q0 = chunk * QPC;
    int q1 = q0 + QPC;
    for (int q = q0 + threadIdx.x; q < q1; q += 256) {
        int4 s = src4[q];
        int4 d = dst4[q];
        unsigned a0 = (unsigned)(d.x - lo); if (a0 < SLICE) esrc[atomicAdd(&cur[a0], 1)] = s.x;
        unsigned a1 = (unsigned)(d.y - lo); if (a1 < SLICE) esrc[atomicAdd(&cur[a1], 1)] = s.y;
        unsigned a2 = (unsigned)(d.z - lo); if (a2 < SLICE) esrc[atomicAdd(&cur[a2], 1)] = s.z;
        unsigned a3 = (unsigned)(d.w - lo); if (a3 < SLICE) esrc[atomicAdd(&cur[a3], 1)] = s.w;
    }
}

// ---------------- z = bf16(out_norm * (feat @ Wc + bc)) via MFMA, LDS-B ----------------
// y-split = 4 (BN=32): 16KB B-panel -> 8 blocks/CU (was 5 at 32KB). feat re-reads
// served by L3 (51MB << 256MB). LDS-B XOR-swizzled on lgkm counter; 2-deep A
// register pipeline. Fragments (m89): A m=lane&15, k=(lane>>4)*8+i; B n=lane&15
// same k; D row=(lane>>4)*4+r, col=lane&15.
__global__ __launch_bounds__(256) void gemm_z(const float* __restrict__ feat,
                                              const ushort_t* __restrict__ Wcs,
                                              const float* __restrict__ bc,
                                              const float* __restrict__ out_norm,
                                              ushort_t* __restrict__ zb) {
    __shared__ ushort_t Bs[32 * IN_DIM];     // 16KB, 512B per col-row, swizzled
    int t    = threadIdx.x;
    int lane = t & 63;
    int wv   = t >> 6;
    int bm   = blockIdx.x * 64 + wv * 16;
    int bn0  = blockIdx.y * 32;
    int mrow = lane & 15;
    int kg   = lane >> 4;
    int gm   = bm + mrow;

    {
        const char* wsrc = (const char*)(Wcs + (size_t)bn0 * IN_DIM);
        char* bdst = (char*)Bs;
#pragma unroll
        for (int p = 0; p < 4; ++p) {
            int d  = p * 4096 + t * 16;
            int ds = d ^ (((d >> 9) & 7) << 4);
            *(int4*)(bdst + ds) = *(const int4*)(wsrc + d);
        }
    }
    __syncthreads();

    f32x4 acc[2];
#pragma unroll
    for (int nt = 0; nt < 2; ++nt) acc[nt] = (f32x4){0.f, 0.f, 0.f, 0.f};

    int boff[2];
#pragma unroll
    for (int nt = 0; nt < 2; ++nt) {
        int n = nt * 16 + mrow;
        boff[nt] = n * 512 + ((kg * 16) ^ ((n & 7) << 4));
    }
    const char* bsp = (const char*)Bs;

    bool valid = gm < N_NODES;
    const float* fp = feat + (size_t)(valid ? gm : 0) * IN_DIM + kg * 8;
    const float4 zf4 = make_float4(0.f, 0.f, 0.f, 0.f);

    float4 a0c = valid ? *(const float4*)(fp + 0) : zf4;
    float4 a1c = valid ? *(const float4*)(fp + 4) : zf4;
    float4 a0n = zf4, a1n = zf4;

#pragma unroll
    for (int kt = 0; kt < IN_DIM / 32; ++kt) {
        if (kt < IN_DIM / 32 - 1) {            // prefetch next kt (2-deep pipeline)
            a0n = valid ? *(const float4*)(fp + (kt + 1) * 32) : zf4;
            a1n = valid ? *(const float4*)(fp + (kt + 1) * 32 + 4) : zf4;
        }
        bf16x8 af;
        af[0] = (short)f2b(a0c.x); af[1] = (short)f2b(a0c.y);
        af[2] = (short)f2b(a0c.z); af[3] = (short)f2b(a0c.w);
        af[4] = (short)f2b(a1c.x); af[5] = (short)f2b(a1c.y);
        af[6] = (short)f2b(a1c.z); af[7] = (short)f2b(a1c.w);
#pragma unroll
        for (int nt = 0; nt < 2; ++nt) {
            bf16x8 bf = *(const bf16x8*)(bsp + (boff[nt] ^ (kt << 6)));
            acc[nt] = __builtin_amdgcn_mfma_f32_16x16x32_bf16(af, bf, acc[nt], 0, 0, 0);
        }
        a0c = a0n; a1c = a1n;
    }

    float on[4];
#pragma unroll
    for (int r = 0; r < 4; ++r) {
        int row = bm + kg * 4 + r;
        on[r] = (row < N_NODES) ? out_norm[row] : 0.f;
    }
#pragma unroll
    for (int nt = 0; nt < 2; ++nt) {
        int col = bn0 + nt * 16 + mrow;
        float bcv = bc[col];
#pragma unroll
        for (int r = 0; r < 4; ++r) {
            int row = bm + kg * 4 + r;
            if (row < N_NODES)
                zb[(size_t)row * OUT_DIM + col] = f2b(on[r] * (acc[nt][r] + bcv));
        }
    }
}

// -------- pull aggregate + fused in_norm/bias/leaky_relu: 4 nodes/wave, uint4 rows --------
__global__ __launch_bounds__(256) void gather_kernel(const uint4* __restrict__ zb4,
                                                     const int* __restrict__ esrc,
                                                     const int* __restrict__ row_ofs,
                                                     const float* __restrict__ in_norm,
                                                     const float* __restrict__ b2,
                                                     uint4* __restrict__ hb4) {
    int n      = blockIdx.x * 16 + (threadIdx.x >> 4);   // grid*16 == N_NODES exactly
    int lane16 = threadIdx.x & 15;
    int e0 = row_ofs[n];
    int e1 = row_ofs[n + 1];
    float ac[8];
#pragma unroll
    for (int i = 0; i < 8; ++i) ac[i] = 0.f;

    int e = e0;
    for (; e + 8 <= e1; e += 8) {
        uint4 v[8];
#pragma unroll
        for (int u = 0; u < 8; ++u) v[u] = zb4[(size_t)esrc[e + u] * 16 + lane16];
#pragma unroll
        for (int u = 0; u < 8; ++u) {
            ac[0] += blo(v[u].x); ac[1] += bhi(v[u].x);
            ac[2] += blo(v[u].y); ac[3] += bhi(v[u].y);
            ac[4] += blo(v[u].z); ac[5] += bhi(v[u].z);
            ac[6] += blo(v[u].w); ac[7] += bhi(v[u].w);
        }
    }
    if (e + 4 <= e1) {
        uint4 v[4];
#pragma unroll
        for (int u = 0; u < 4; ++u) v[u] = zb4[(size_t)esrc[e + u] * 16 + lane16];
#pragma unroll
        for (int u = 0; u < 4; ++u) {
            ac[0] += blo(v[u].x); ac[1] += bhi(v[u].x);
            ac[2] += blo(v[u].y); ac[3] += bhi(v[u].y);
            ac[4] += blo(v[u].z); ac[5] += bhi(v[u].z);
            ac[6] += blo(v[u].w); ac[7] += bhi(v[u].w);
        }
        e += 4;
    }
    for (; e < e1; ++e) {
        uint4 v = zb4[(size_t)esrc[e] * 16 + lane16];
        ac[0] += blo(v.x); ac[1] += bhi(v.x);
        ac[2] += blo(v.y); ac[3] += bhi(v.y);
        ac[4] += blo(v.z); ac[5] += bhi(v.z);
        ac[6] += blo(v.w); ac[7] += bhi(v.w);
    }

    float inn = in_norm[n];
    float4 bA = *(const float4*)&b2[lane16 * 8];
    float4 bB = *(const float4*)&b2[lane16 * 8 + 4];
    float hv[8];
    hv[0] = fmaf(inn, ac[0], bA.x); hv[1] = fmaf(inn, ac[1], bA.y);
    hv[2] = fmaf(inn, ac[2], bA.z); hv[3] = fmaf(inn, ac[3], bA.w);
    hv[4] = fmaf(inn, ac[4], bB.x); hv[5] = fmaf(inn, ac[5], bB.y);
    hv[6] = fmaf(inn, ac[6], bB.z); hv[7] = fmaf(inn, ac[7], bB.w);
#pragma unroll
    for (int i = 0; i < 8; ++i) hv[i] = (hv[i] > 0.f) ? hv[i] : NEG_SLOPE * hv[i];
    uint4 o;
    o.x = (uint_t)f2b(hv[0]) | ((uint_t)f2b(hv[1]) << 16);
    o.y = (uint_t)f2b(hv[2]) | ((uint_t)f2b(hv[3]) << 16);
    o.z = (uint_t)f2b(hv[4]) | ((uint_t)f2b(hv[5]) << 16);
    o.w = (uint_t)f2b(hv[6]) | ((uint_t)f2b(hv[7]) << 16);
    hb4[(size_t)n * 16 + lane16] = o;
}

// ------- per-graph readout: one wave per 64-node chunk, packed uint col-pairs -------
__global__ __launch_bounds__(64) void readout_kernel(const uint_t* __restrict__ hb2,
                                                     const int* __restrict__ gids,
                                                     float* __restrict__ g) {
    int t    = threadIdx.x;                  // 0..63
    int n0   = blockIdx.x * RCHUNK;
    int nend = n0 + RCHUNK;
    if (nend > N_NODES) nend = N_NODES;
    float acc0 = 0.f, acc1 = 0.f;
    int   cur = gids[n0];
    for (int n = n0; n < nend; ++n) {
        int gid = gids[n];
        if (gid != cur) {
            atomicAdd(&g[cur * OUT_DIM + 2 * t], acc0);
            atomicAdd(&g[cur * OUT_DIM + 2 * t + 1], acc1);
            acc0 = acc1 = 0.f;
            cur = gid;
        }
        uint_t v = hb2[(size_t)n * 64 + t];
        acc0 += blo(v);
        acc1 += bhi(v);
    }
    atomicAdd(&g[cur * OUT_DIM + 2 * t], acc0);
    atomicAdd(&g[cur * OUT_DIM + 2 * t + 1], acc1);
}

// ---------------- classifier: out = g @ w_cls + b_cls ----------------
__global__ __launch_bounds__(256) void cls_kernel(const float* __restrict__ g,
                                                  const float* __restrict__ w_cls,
                                                  const float* __restrict__ b_cls,
                                                  float* __restrict__ out) {
    int t  = threadIdx.x;
    int gr = t >> 1;
    int c  = t & 1;
    float s = b_cls[c];
    for (int k = 0; k < OUT_DIM; ++k) s = fmaf(g[gr * OUT_DIM + k], w_cls[k * 2 + c], s);
    out[t] = s;
}

extern "C" void kernel_launch(void* const* d_in, const int* in_sizes, int n_in,
                              void* d_out, int out_size, void* d_ws, size_t ws_size,
                              hipStream_t stream) {
    const float* feat  = (const float*)d_in[0];
    const int*   src   = (const int*)d_in[1];
    const int*   dst   = (const int*)d_in[2];
    const int*   gids  = (const int*)d_in[3];
    const float* w_red = (const float*)d_in[4];
    const float* b_red = (const float*)d_in[5];
    const float* w_gcn = (const float*)d_in[6];
    const float* b_gcn = (const float*)d_in[7];
    const float* w_cls = (const float*)d_in[8];
    const float* b_cls = (const float*)d_in[9];
    float* out = (float*)d_out;

    // workspace layout (z/h regions sized as fp32 but used as bf16 -> half used)
    float* z        = (float*)d_ws;                       // 25.6MB region; zb uses 12.8
    float* h        = z + (size_t)N_NODES * OUT_DIM;      // 25.6MB region; hb uses 12.8
    float* out_norm = h + (size_t)N_NODES * OUT_DIM;      // 50000
    float* in_norm  = out_norm + N_NODES;                 // 50000
    int*   deg_in   = (int*)(in_norm + N_NODES);          // 50000 (compact)
    int*   row_ofs  = deg_in + N_NODES;                   // 50001
    int*   esrc     = row_ofs + N_NODES + 1;              // 800000
    int*   bsum     = esrc + N_EDGES;                     // NB_SCAN
    ushort_t* Wcs   = (ushort_t*)(bsum + NB_SCAN);        // 32768 bf16
    float* bc       = (float*)(Wcs + IN_DIM * OUT_DIM);   // 128
    float* g        = bc + OUT_DIM;                       // 16384

    ushort_t* zb = (ushort_t*)z;
    ushort_t* hb = (ushort_t*)h;

    // u16 per-chunk histograms rep[2][NCHUNK][NTOT] = 12.8MB ALIAS z region
    // (deg/norm/build all complete before gemm_z writes zb).
    ushort_t* rep = (ushort_t*)z;

    const float* w2 = w_gcn + 2 * OUT_DIM * OUT_DIM;      // layer 2 weights
    const float* b2 = b_gcn + 2 * OUT_DIM;                // layer 2 bias

    deg_kernel<<<2 * NSLICE * NCHUNK, 256, 0, stream>>>((const int4*)src, (const int4*)dst, rep);
    norm_kernel<<<NB_SCAN, 256, 0, stream>>>(rep, out_norm, in_norm, deg_in, bsum);
    fillwc_kernel<<<NB_SCAN + IN_DIM + 1, 256, 0, stream>>>(deg_in, bsum, row_ofs,
                                                            w_red, b_red, w2, Wcs, bc, g);
    build_kernel<<<NSLICE * NCHUNK, 256, 0, stream>>>((const int4*)src, (const int4*)dst,
                                                      row_ofs, rep, esrc);
    gemm_z<<<dim3((N_NODES + 63) / 64, 4), 256, 0, stream>>>(feat, Wcs, bc, out_norm, zb);
    gather_kernel<<<N_NODES / 16, 256, 0, stream>>>((const uint4*)zb, esrc, row_ofs,
                                                    in_norm, b2, (uint4*)hb);
    readout_kernel<<<(N_NODES + RCHUNK - 1) / RCHUNK, 64, 0, stream>>>((const uint_t*)hb,
                                                                       gids, g);
    cls_kernel<<<1, 256, 0, stream>>>(g, w_cls, b_cls, out);
}

// Round 15
// 151.201 us; speedup vs baseline: 1.0744x; 1.0744x over previous
//
#include <hip/hip_runtime.h>

#define N_NODES 50000
#define N_EDGES 800000
#define N_GRAPHS 128
#define IN_DIM 256
#define OUT_DIM 128
#define NEG_SLOPE 0.01f

#define RCHUNK 64
#define NB_SCAN ((N_NODES + 255) / 256)   // 196 blocks for the scan

#define NSLICE 4
#define SLICE 12544                        // 4*12544 = 50176 >= N_NODES
#define NTOT (NSLICE * SLICE)              // 50176
#define NCHUNK 64
#define NE4 (N_EDGES / 4)                  // 200000 int4 quads
#define QPC (NE4 / NCHUNK)                 // 3125 quads per chunk

typedef __attribute__((ext_vector_type(8))) short bf16x8;
typedef __attribute__((ext_vector_type(4))) float f32x4;
typedef unsigned short ushort_t;
typedef unsigned int uint_t;

__device__ inline ushort_t f2b(float f) {          // fp32 -> bf16 bits, RNE
    union { float f; unsigned u; } c{f};
    unsigned r = c.u + 0x7FFFu + ((c.u >> 16) & 1u);
    return (ushort_t)(r >> 16);
}
__device__ inline float b2f(ushort_t u) {          // bf16 bits -> fp32
    union { unsigned u; float f; } c{(unsigned)u << 16};
    return c.f;
}
__device__ inline float blo(uint_t v) {            // low bf16 of packed pair
    union { unsigned u; float f; } c{v << 16};
    return c.f;
}
__device__ inline float bhi(uint_t v) {            // high bf16 of packed pair
    union { unsigned u; float f; } c{v & 0xFFFF0000u};
    return c.f;
}

// ------- degree histograms: packed-u16 LDS bins (25KB), zero global atomics -------
// bins32[i] holds counts for nodes {2i (lo16), 2i+1 (hi16)}; counts <= 12500 so
// no carry across the halves. Matches rep's packed-u16 pair format directly.
__global__ __launch_bounds__(256) void deg_kernel(const int4* __restrict__ src4,
                                                  const int4* __restrict__ dst4,
                                                  ushort_t* __restrict__ rep) {
    __shared__ uint_t bins[SLICE / 2];   // 25KB -> 6 blocks/CU
    int b     = blockIdx.x;
    int hist  = b >> 8;                  // 0: src (out-deg), 1: dst (in-deg)
    int rem   = b & 255;
    int slice = rem >> 6;
    int chunk = rem & 63;
    const int4* ea = hist ? dst4 : src4;
    int lo = slice * SLICE;

    for (int i = threadIdx.x; i < SLICE / 2; i += 256) bins[i] = 0;
    __syncthreads();

    int q0 = chunk * QPC;
    int q1 = q0 + QPC;
    for (int q = q0 + threadIdx.x; q < q1; q += 256) {
        int4 e = ea[q];
        unsigned a0 = (unsigned)(e.x - lo);
        if (a0 < SLICE) atomicAdd(&bins[a0 >> 1], 1u << ((a0 & 1) << 4));
        unsigned a1 = (unsigned)(e.y - lo);
        if (a1 < SLICE) atomicAdd(&bins[a1 >> 1], 1u << ((a1 & 1) << 4));
        unsigned a2 = (unsigned)(e.z - lo);
        if (a2 < SLICE) atomicAdd(&bins[a2 >> 1], 1u << ((a2 & 1) << 4));
        unsigned a3 = (unsigned)(e.w - lo);
        if (a3 < SLICE) atomicAdd(&bins[a3 >> 1], 1u << ((a3 & 1) << 4));
    }
    __syncthreads();

    uint_t* rp32 = (uint_t*)(rep + (size_t)(hist * NCHUNK + chunk) * NTOT + lo);
    for (int i = threadIdx.x; i < SLICE / 2; i += 256)
        rp32[i] = bins[i];
}

// ---- reduce replicas -> norms + deg_in; in-place chunk-prefix scan; fused block sums ----
__global__ __launch_bounds__(256) void norm_kernel(ushort_t* __restrict__ rep,
                                                   float* __restrict__ out_norm,
                                                   float* __restrict__ in_norm,
                                                   int* __restrict__ deg_in_tot,
                                                   int* __restrict__ bsum) {
    __shared__ int red[256];
    int t = threadIdx.x;
    int i = blockIdx.x * 256 + t;
    int si_keep = 0;
    if (i < N_NODES) {
        int so = 0;
#pragma unroll
        for (int c = 0; c < NCHUNK; ++c) so += rep[(size_t)c * NTOT + i];
        int si = 0;
#pragma unroll
        for (int c = 0; c < NCHUNK; ++c) {       // exclusive scan, in place
            size_t off = (size_t)(NCHUNK + c) * NTOT + i;
            int v = rep[off];
            rep[off] = (ushort_t)si;
            si += v;
        }
        deg_in_tot[i] = si;
        si_keep = si;
        int dq = so > 1 ? so : 1;
        int di = si > 1 ? si : 1;
        out_norm[i] = rsqrtf((float)dq);
        in_norm[i]  = rsqrtf((float)di);
    }
    red[t] = si_keep;
    __syncthreads();
    for (int off = 128; off > 0; off >>= 1) {
        if (t < off) red[t] += red[t + off];
        __syncthreads();
    }
    if (t == 0) bsum[blockIdx.x] = red[0];
}

// ---- merged fill + wc: blocks 0..195 build row_ofs; blocks 196..452 fold weights ----
__global__ __launch_bounds__(256) void fillwc_kernel(const int* __restrict__ deg_in,
                                                     const int* __restrict__ bsum,
                                                     int* __restrict__ row_ofs,
                                                     const float* __restrict__ w_red,
                                                     const float* __restrict__ b_red,
                                                     const float* __restrict__ w2,
                                                     ushort_t* __restrict__ Wcs,
                                                     float* __restrict__ bc,
                                                     float* __restrict__ g) {
    int t   = threadIdx.x;
    int bid = blockIdx.x;

    if (bid < NB_SCAN) {
        // ---------- fill part ----------
        __shared__ int sh[256];
        // phase A: scan block sums
        int v = (t < NB_SCAN) ? bsum[t] : 0;
        sh[t] = v;
        __syncthreads();
        for (int off = 1; off < 256; off <<= 1) {
            int a = sh[t];
            int b = (t >= off) ? sh[t - off] : 0;
            __syncthreads();
            sh[t] = a + b;
            __syncthreads();
        }
        int bofs  = sh[bid] - bsum[bid];          // exclusive prefix of this block
        int total = sh[NB_SCAN - 1];
        __syncthreads();

        // phase B: block-local scan of degrees
        int idx = bid * 256 + t;
        int dv  = (idx < N_NODES) ? deg_in[idx] : 0;
        sh[t] = dv;
        __syncthreads();
        for (int off = 1; off < 256; off <<= 1) {
            int a = sh[t];
            int b = (t >= off) ? sh[t - off] : 0;
            __syncthreads();
            sh[t] = a + b;
            __syncthreads();
        }
        if (idx < N_NODES) row_ofs[idx] = bofs + sh[t] - dv;
        if (bid == 0 && t == 0) row_ofs[N_NODES] = total;   // = N_EDGES
    } else if (t < OUT_DIM) {
        // ---------- wc part: Wcs[n][k] = bf16(sum_c w_red[k][c] w2[c][n]) ----------
        int i = bid - NB_SCAN;   // k: 0..256 (i==IN_DIM computes bc)
        int j = t;               // n: 0..127
        if (i < N_GRAPHS) g[i * OUT_DIM + j] = 0.f;   // zero g (replaces memset)
        const float* vin = (i < IN_DIM) ? (w_red + (size_t)i * OUT_DIM) : b_red;
        float s = 0.f;
        for (int k = 0; k < OUT_DIM; ++k) s = fmaf(vin[k], w2[k * OUT_DIM + j], s);
        if (i < IN_DIM) Wcs[(size_t)j * IN_DIM + i] = f2b(s);   // transposed, bf16
        else            bc[j] = s;
    }
}

// ---------------- chunked bucket fill: LDS cursors, zero global atomics ----------------
__global__ __launch_bounds__(256) void build_kernel(const int4* __restrict__ src4,
                                                    const int4* __restrict__ dst4,
                                                    const int* __restrict__ row_ofs,
                                                    const ushort_t* __restrict__ rep,
                                                    int* __restrict__ esrc) {
    __shared__ int cur[SLICE];
    int b     = blockIdx.x;
    int slice = b >> 6;
    int chunk = b & 63;
    int lo    = slice * SLICE;
    const ushort_t* rel = rep + (size_t)(NCHUNK + chunk) * NTOT + lo;

    for (int i = threadIdx.x; i < SLICE; i += 256) {
        int n = lo + i;
        int r = (n < N_NODES) ? row_ofs[n] : 0;
        cur[i] = r + (int)rel[i];
    }
    __syncthreads();

    int q0 = chunk * QPC;
    int q1 = q0 + QPC;
    for (int q = q0 + threadIdx.x; q < q1; q += 256) {
        int4 s = src4[q];
        int4 d = dst4[q];
        unsigned a0 = (unsigned)(d.x - lo); if (a0 < SLICE) esrc[atomicAdd(&cur[a0], 1)] = s.x;
        unsigned a1 = (unsigned)(d.y - lo); if (a1 < SLICE) esrc[atomicAdd(&cur[a1], 1)] = s.y;
        unsigned a2 = (unsigned)(d.z - lo); if (a2 < SLICE) esrc[atomicAdd(&cur[a2], 1)] = s.z;
        unsigned a3 = (unsigned)(d.w - lo); if (a3 < SLICE) esrc[atomicAdd(&cur[a3], 1)] = s.w;
    }
}

// ---------------- z = bf16(out_norm * (feat @ Wc + bc)) via MFMA, LDS-B ----------------
// y-split = 2 (BN=64, 32KB B-panel): R13's proven config — feat read only 2x,
// FETCH ~25MB (R14's y=4 read feat 4x -> 100MB HBM, gemm went HBM-bound).
// LDS-B XOR-swizzled on lgkm counter; 2-deep A register pipeline. Fragments
// (m89): A m=lane&15, k=(lane>>4)*8+i; B n=lane&15 same k; D row=(lane>>4)*4+r,
// col=lane&15.
__global__ __launch_bounds__(256) void gemm_z(const float* __restrict__ feat,
                                              const ushort_t* __restrict__ Wcs,
                                              const float* __restrict__ bc,
                                              const float* __restrict__ out_norm,
                                              ushort_t* __restrict__ zb) {
    __shared__ ushort_t Bs[64 * IN_DIM];     // 32KB, 512B per col-row, swizzled
    int t    = threadIdx.x;
    int lane = t & 63;
    int wv   = t >> 6;
    int bm   = blockIdx.x * 64 + wv * 16;
    int bn0  = blockIdx.y * 64;
    int mrow = lane & 15;
    int kg   = lane >> 4;
    int gm   = bm + mrow;

    {
        const char* wsrc = (const char*)(Wcs + (size_t)bn0 * IN_DIM);
        char* bdst = (char*)Bs;
#pragma unroll
        for (int p = 0; p < 8; ++p) {
            int d  = p * 4096 + t * 16;
            int ds = d ^ (((d >> 9) & 7) << 4);
            *(int4*)(bdst + ds) = *(const int4*)(wsrc + d);
        }
    }
    __syncthreads();

    f32x4 acc[4];
#pragma unroll
    for (int nt = 0; nt < 4; ++nt) acc[nt] = (f32x4){0.f, 0.f, 0.f, 0.f};

    int boff[4];
#pragma unroll
    for (int nt = 0; nt < 4; ++nt) {
        int n = nt * 16 + mrow;
        boff[nt] = n * 512 + ((kg * 16) ^ ((n & 7) << 4));
    }
    const char* bsp = (const char*)Bs;

    bool valid = gm < N_NODES;
    const float* fp = feat + (size_t)(valid ? gm : 0) * IN_DIM + kg * 8;
    const float4 zf4 = make_float4(0.f, 0.f, 0.f, 0.f);

    float4 a0c = valid ? *(const float4*)(fp + 0) : zf4;
    float4 a1c = valid ? *(const float4*)(fp + 4) : zf4;
    float4 a0n = zf4, a1n = zf4;

#pragma unroll
    for (int kt = 0; kt < IN_DIM / 32; ++kt) {
        if (kt < IN_DIM / 32 - 1) {            // prefetch next kt (2-deep pipeline)
            a0n = valid ? *(const float4*)(fp + (kt + 1) * 32) : zf4;
            a1n = valid ? *(const float4*)(fp + (kt + 1) * 32 + 4) : zf4;
        }
        bf16x8 af;
        af[0] = (short)f2b(a0c.x); af[1] = (short)f2b(a0c.y);
        af[2] = (short)f2b(a0c.z); af[3] = (short)f2b(a0c.w);
        af[4] = (short)f2b(a1c.x); af[5] = (short)f2b(a1c.y);
        af[6] = (short)f2b(a1c.z); af[7] = (short)f2b(a1c.w);
#pragma unroll
        for (int nt = 0; nt < 4; ++nt) {
            bf16x8 bf = *(const bf16x8*)(bsp + (boff[nt] ^ (kt << 6)));
            acc[nt] = __builtin_amdgcn_mfma_f32_16x16x32_bf16(af, bf, acc[nt], 0, 0, 0);
        }
        a0c = a0n; a1c = a1n;
    }

    float on[4];
#pragma unroll
    for (int r = 0; r < 4; ++r) {
        int row = bm + kg * 4 + r;
        on[r] = (row < N_NODES) ? out_norm[row] : 0.f;
    }
#pragma unroll
    for (int nt = 0; nt < 4; ++nt) {
        int col = bn0 + nt * 16 + mrow;
        float bcv = bc[col];
#pragma unroll
        for (int r = 0; r < 4; ++r) {
            int row = bm + kg * 4 + r;
            if (row < N_NODES)
                zb[(size_t)row * OUT_DIM + col] = f2b(on[r] * (acc[nt][r] + bcv));
        }
    }
}

// -------- pull aggregate + fused in_norm/bias/leaky_relu: 4 nodes/wave, uint4 rows --------
__global__ __launch_bounds__(256) void gather_kernel(const uint4* __restrict__ zb4,
                                                     const int* __restrict__ esrc,
                                                     const int* __restrict__ row_ofs,
                                                     const float* __restrict__ in_norm,
                                                     const float* __restrict__ b2,
                                                     uint4* __restrict__ hb4) {
    int n      = blockIdx.x * 16 + (threadIdx.x >> 4);   // grid*16 == N_NODES exactly
    int lane16 = threadIdx.x & 15;
    int e0 = row_ofs[n];
    int e1 = row_ofs[n + 1];
    float ac[8];
#pragma unroll
    for (int i = 0; i < 8; ++i) ac[i] = 0.f;

    int e = e0;
    for (; e + 8 <= e1; e += 8) {
        uint4 v[8];
#pragma unroll
        for (int u = 0; u < 8; ++u) v[u] = zb4[(size_t)esrc[e + u] * 16 + lane16];
#pragma unroll
        for (int u = 0; u < 8; ++u) {
            ac[0] += blo(v[u].x); ac[1] += bhi(v[u].x);
            ac[2] += blo(v[u].y); ac[3] += bhi(v[u].y);
            ac[4] += blo(v[u].z); ac[5] += bhi(v[u].z);
            ac[6] += blo(v[u].w); ac[7] += bhi(v[u].w);
        }
    }
    if (e + 4 <= e1) {
        uint4 v[4];
#pragma unroll
        for (int u = 0; u < 4; ++u) v[u] = zb4[(size_t)esrc[e + u] * 16 + lane16];
#pragma unroll
        for (int u = 0; u < 4; ++u) {
            ac[0] += blo(v[u].x); ac[1] += bhi(v[u].x);
            ac[2] += blo(v[u].y); ac[3] += bhi(v[u].y);
            ac[4] += blo(v[u].z); ac[5] += bhi(v[u].z);
            ac[6] += blo(v[u].w); ac[7] += bhi(v[u].w);
        }
        e += 4;
    }
    for (; e < e1; ++e) {
        uint4 v = zb4[(size_t)esrc[e] * 16 + lane16];
        ac[0] += blo(v.x); ac[1] += bhi(v.x);
        ac[2] += blo(v.y); ac[3] += bhi(v.y);
        ac[4] += blo(v.z); ac[5] += bhi(v.z);
        ac[6] += blo(v.w); ac[7] += bhi(v.w);
    }

    float inn = in_norm[n];
    float4 bA = *(const float4*)&b2[lane16 * 8];
    float4 bB = *(const float4*)&b2[lane16 * 8 + 4];
    float hv[8];
    hv[0] = fmaf(inn, ac[0], bA.x); hv[1] = fmaf(inn, ac[1], bA.y);
    hv[2] = fmaf(inn, ac[2], bA.z); hv[3] = fmaf(inn, ac[3], bA.w);
    hv[4] = fmaf(inn, ac[4], bB.x); hv[5] = fmaf(inn, ac[5], bB.y);
    hv[6] = fmaf(inn, ac[6], bB.z); hv[7] = fmaf(inn, ac[7], bB.w);
#pragma unroll
    for (int i = 0; i < 8; ++i) hv[i] = (hv[i] > 0.f) ? hv[i] : NEG_SLOPE * hv[i];
    uint4 o;
    o.x = (uint_t)f2b(hv[0]) | ((uint_t)f2b(hv[1]) << 16);
    o.y = (uint_t)f2b(hv[2]) | ((uint_t)f2b(hv[3]) << 16);
    o.z = (uint_t)f2b(hv[4]) | ((uint_t)f2b(hv[5]) << 16);
    o.w = (uint_t)f2b(hv[6]) | ((uint_t)f2b(hv[7]) << 16);
    hb4[(size_t)n * 16 + lane16] = o;
}

// ------- per-graph readout: one wave per 64-node chunk, packed uint col-pairs -------
__global__ __launch_bounds__(64) void readout_kernel(const uint_t* __restrict__ hb2,
                                                     const int* __restrict__ gids,
                                                     float* __restrict__ g) {
    int t    = threadIdx.x;                  // 0..63
    int n0   = blockIdx.x * RCHUNK;
    int nend = n0 + RCHUNK;
    if (nend > N_NODES) nend = N_NODES;
    float acc0 = 0.f, acc1 = 0.f;
    int   cur = gids[n0];
    for (int n = n0; n < nend; ++n) {
        int gid = gids[n];
        if (gid != cur) {
            atomicAdd(&g[cur * OUT_DIM + 2 * t], acc0);
            atomicAdd(&g[cur * OUT_DIM + 2 * t + 1], acc1);
            acc0 = acc1 = 0.f;
            cur = gid;
        }
        uint_t v = hb2[(size_t)n * 64 + t];
        acc0 += blo(v);
        acc1 += bhi(v);
    }
    atomicAdd(&g[cur * OUT_DIM + 2 * t], acc0);
    atomicAdd(&g[cur * OUT_DIM + 2 * t + 1], acc1);
}

// ---------------- classifier: out = g @ w_cls + b_cls ----------------
__global__ __launch_bounds__(256) void cls_kernel(const float* __restrict__ g,
                                                  const float* __restrict__ w_cls,
                                                  const float* __restrict__ b_cls,
                                                  float* __restrict__ out) {
    int t  = threadIdx.x;
    int gr = t >> 1;
    int c  = t & 1;
    float s = b_cls[c];
    for (int k = 0; k < OUT_DIM; ++k) s = fmaf(g[gr * OUT_DIM + k], w_cls[k * 2 + c], s);
    out[t] = s;
}

extern "C" void kernel_launch(void* const* d_in, const int* in_sizes, int n_in,
                              void* d_out, int out_size, void* d_ws, size_t ws_size,
                              hipStream_t stream) {
    const float* feat  = (const float*)d_in[0];
    const int*   src   = (const int*)d_in[1];
    const int*   dst   = (const int*)d_in[2];
    const int*   gids  = (const int*)d_in[3];
    const float* w_red = (const float*)d_in[4];
    const float* b_red = (const float*)d_in[5];
    const float* w_gcn = (const float*)d_in[6];
    const float* b_gcn = (const float*)d_in[7];
    const float* w_cls = (const float*)d_in[8];
    const float* b_cls = (const float*)d_in[9];
    float* out = (float*)d_out;

    // workspace layout (z/h regions sized as fp32 but used as bf16 -> half used)
    float* z        = (float*)d_ws;                       // 25.6MB region; zb uses 12.8
    float* h        = z + (size_t)N_NODES * OUT_DIM;      // 25.6MB region; hb uses 12.8
    float* out_norm = h + (size_t)N_NODES * OUT_DIM;      // 50000
    float* in_norm  = out_norm + N_NODES;                 // 50000
    int*   deg_in   = (int*)(in_norm + N_NODES);          // 50000 (compact)
    int*   row_ofs  = deg_in + N_NODES;                   // 50001
    int*   esrc     = row_ofs + N_NODES + 1;              // 800000
    int*   bsum     = esrc + N_EDGES;                     // NB_SCAN
    ushort_t* Wcs   = (ushort_t*)(bsum + NB_SCAN);        // 32768 bf16
    float* bc       = (float*)(Wcs + IN_DIM * OUT_DIM);   // 128
    float* g        = bc + OUT_DIM;                       // 16384

    ushort_t* zb = (ushort_t*)z;
    ushort_t* hb = (ushort_t*)h;

    // u16 per-chunk histograms rep[2][NCHUNK][NTOT] = 12.8MB ALIAS z region
    // (deg/norm/build all complete before gemm_z writes zb).
    ushort_t* rep = (ushort_t*)z;

    const float* w2 = w_gcn + 2 * OUT_DIM * OUT_DIM;      // layer 2 weights
    const float* b2 = b_gcn + 2 * OUT_DIM;                // layer 2 bias

    deg_kernel<<<2 * NSLICE * NCHUNK, 256, 0, stream>>>((const int4*)src, (const int4*)dst, rep);
    norm_kernel<<<NB_SCAN, 256, 0, stream>>>(rep, out_norm, in_norm, deg_in, bsum);
    fillwc_kernel<<<NB_SCAN + IN_DIM + 1, 256, 0, stream>>>(deg_in, bsum, row_ofs,
                                                            w_red, b_red, w2, Wcs, bc, g);
    build_kernel<<<NSLICE * NCHUNK, 256, 0, stream>>>((const int4*)src, (const int4*)dst,
                                                      row_ofs, rep, esrc);
    gemm_z<<<dim3((N_NODES + 63) / 64, 2), 256, 0, stream>>>(feat, Wcs, bc, out_norm, zb);
    gather_kernel<<<N_NODES / 16, 256, 0, stream>>>((const uint4*)zb, esrc, row_ofs,
                                                    in_norm, b2, (uint4*)hb);
    readout_kernel<<<(N_NODES + RCHUNK - 1) / RCHUNK, 64, 0, stream>>>((const uint_t*)hb,
                                                                       gids, g);
    cls_kernel<<<1, 256, 0, stream>>>(g, w_cls, b_cls, out);
}

// Round 16
// 146.900 us; speedup vs baseline: 1.1058x; 1.0293x over previous
//
#include <hip/hip_runtime.h>

#define N_NODES 50000
#define N_EDGES 800000
#define N_GRAPHS 128
#define IN_DIM 256
#define OUT_DIM 128
#define NEG_SLOPE 0.01f

#define RCHUNK 64
#define NB_SCAN ((N_NODES + 255) / 256)   // 196 blocks for the scan

#define NSLICE 4
#define SLICE 12544                        // 4*12544 = 50176 >= N_NODES
#define NTOT (NSLICE * SLICE)              // 50176
#define NCHUNK 64
#define NE4 (N_EDGES / 4)                  // 200000 int4 quads
#define QPC (NE4 / NCHUNK)                 // 3125 quads per chunk

typedef __attribute__((ext_vector_type(8))) short bf16x8;
typedef __attribute__((ext_vector_type(4))) float f32x4;
typedef unsigned short ushort_t;
typedef unsigned int uint_t;

__device__ inline ushort_t f2b(float f) {          // fp32 -> bf16 bits, RNE
    union { float f; unsigned u; } c{f};
    unsigned r = c.u + 0x7FFFu + ((c.u >> 16) & 1u);
    return (ushort_t)(r >> 16);
}
__device__ inline float b2f(ushort_t u) {          // bf16 bits -> fp32
    union { unsigned u; float f; } c{(unsigned)u << 16};
    return c.f;
}
__device__ inline float blo(uint_t v) {            // low bf16 of packed pair
    union { unsigned u; float f; } c{v << 16};
    return c.f;
}
__device__ inline float bhi(uint_t v) {            // high bf16 of packed pair
    union { unsigned u; float f; } c{v & 0xFFFF0000u};
    return c.f;
}

// ------- degree histograms: packed-u16 LDS bins (25KB), zero global atomics -------
__global__ __launch_bounds__(256) void deg_kernel(const int4* __restrict__ src4,
                                                  const int4* __restrict__ dst4,
                                                  ushort_t* __restrict__ rep) {
    __shared__ uint_t bins[SLICE / 2];   // 25KB -> 6 blocks/CU
    int b     = blockIdx.x;
    int hist  = b >> 8;                  // 0: src (out-deg), 1: dst (in-deg)
    int rem   = b & 255;
    int slice = rem >> 6;
    int chunk = rem & 63;
    const int4* ea = hist ? dst4 : src4;
    int lo = slice * SLICE;

    for (int i = threadIdx.x; i < SLICE / 2; i += 256) bins[i] = 0;
    __syncthreads();

    int q0 = chunk * QPC;
    int q1 = q0 + QPC;
    for (int q = q0 + threadIdx.x; q < q1; q += 256) {
        int4 e = ea[q];
        unsigned a0 = (unsigned)(e.x - lo);
        if (a0 < SLICE) atomicAdd(&bins[a0 >> 1], 1u << ((a0 & 1) << 4));
        unsigned a1 = (unsigned)(e.y - lo);
        if (a1 < SLICE) atomicAdd(&bins[a1 >> 1], 1u << ((a1 & 1) << 4));
        unsigned a2 = (unsigned)(e.z - lo);
        if (a2 < SLICE) atomicAdd(&bins[a2 >> 1], 1u << ((a2 & 1) << 4));
        unsigned a3 = (unsigned)(e.w - lo);
        if (a3 < SLICE) atomicAdd(&bins[a3 >> 1], 1u << ((a3 & 1) << 4));
    }
    __syncthreads();

    uint_t* rp32 = (uint_t*)(rep + (size_t)(hist * NCHUNK + chunk) * NTOT + lo);
    for (int i = threadIdx.x; i < SLICE / 2; i += 256)
        rp32[i] = bins[i];
}

// ---- reduce replicas -> norms + deg_in; in-place chunk-prefix scan; fused block sums ----
__global__ __launch_bounds__(256) void norm_kernel(ushort_t* __restrict__ rep,
                                                   float* __restrict__ out_norm,
                                                   float* __restrict__ in_norm,
                                                   int* __restrict__ deg_in_tot,
                                                   int* __restrict__ bsum) {
    __shared__ int red[256];
    int t = threadIdx.x;
    int i = blockIdx.x * 256 + t;
    int si_keep = 0;
    if (i < N_NODES) {
        int so = 0;
#pragma unroll
        for (int c = 0; c < NCHUNK; ++c) so += rep[(size_t)c * NTOT + i];
        int si = 0;
#pragma unroll
        for (int c = 0; c < NCHUNK; ++c) {       // exclusive scan, in place
            size_t off = (size_t)(NCHUNK + c) * NTOT + i;
            int v = rep[off];
            rep[off] = (ushort_t)si;
            si += v;
        }
        deg_in_tot[i] = si;
        si_keep = si;
        int dq = so > 1 ? so : 1;
        int di = si > 1 ? si : 1;
        out_norm[i] = rsqrtf((float)dq);
        in_norm[i]  = rsqrtf((float)di);
    }
    red[t] = si_keep;
    __syncthreads();
    for (int off = 128; off > 0; off >>= 1) {
        if (t < off) red[t] += red[t + off];
        __syncthreads();
    }
    if (t == 0) bsum[blockIdx.x] = red[0];
}

// ---- merged fill + wc: blocks 0..195 build row_ofs; blocks 196..452 fold weights ----
__global__ __launch_bounds__(256) void fillwc_kernel(const int* __restrict__ deg_in,
                                                     const int* __restrict__ bsum,
                                                     int* __restrict__ row_ofs,
                                                     const float* __restrict__ w_red,
                                                     const float* __restrict__ b_red,
                                                     const float* __restrict__ w2,
                                                     ushort_t* __restrict__ Wcs,
                                                     float* __restrict__ bc) {
    int t   = threadIdx.x;
    int bid = blockIdx.x;

    if (bid < NB_SCAN) {
        // ---------- fill part ----------
        __shared__ int sh[256];
        // phase A: scan block sums
        int v = (t < NB_SCAN) ? bsum[t] : 0;
        sh[t] = v;
        __syncthreads();
        for (int off = 1; off < 256; off <<= 1) {
            int a = sh[t];
            int b = (t >= off) ? sh[t - off] : 0;
            __syncthreads();
            sh[t] = a + b;
            __syncthreads();
        }
        int bofs  = sh[bid] - bsum[bid];          // exclusive prefix of this block
        int total = sh[NB_SCAN - 1];
        __syncthreads();

        // phase B: block-local scan of degrees
        int idx = bid * 256 + t;
        int dv  = (idx < N_NODES) ? deg_in[idx] : 0;
        sh[t] = dv;
        __syncthreads();
        for (int off = 1; off < 256; off <<= 1) {
            int a = sh[t];
            int b = (t >= off) ? sh[t - off] : 0;
            __syncthreads();
            sh[t] = a + b;
            __syncthreads();
        }
        if (idx < N_NODES) row_ofs[idx] = bofs + sh[t] - dv;
        if (bid == 0 && t == 0) row_ofs[N_NODES] = total;   // = N_EDGES
    } else if (t < OUT_DIM) {
        // ---------- wc part: Wcs[n][k] = bf16(sum_c w_red[k][c] w2[c][n]) ----------
        int i = bid - NB_SCAN;   // k: 0..256 (i==IN_DIM computes bc)
        int j = t;               // n: 0..127
        const float* vin = (i < IN_DIM) ? (w_red + (size_t)i * OUT_DIM) : b_red;
        float s = 0.f;
        for (int k = 0; k < OUT_DIM; ++k) s = fmaf(vin[k], w2[k * OUT_DIM + j], s);
        if (i < IN_DIM) Wcs[(size_t)j * IN_DIM + i] = f2b(s);   // transposed, bf16
        else            bc[j] = s;
    }
}

// ---------------- chunked bucket fill: LDS cursors, zero global atomics ----------------
__global__ __launch_bounds__(256) void build_kernel(const int4* __restrict__ src4,
                                                    const int4* __restrict__ dst4,
                                                    const int* __restrict__ row_ofs,
                                                    const ushort_t* __restrict__ rep,
                                                    int* __restrict__ esrc) {
    __shared__ int cur[SLICE];
    int b     = blockIdx.x;
    int slice = b >> 6;
    int chunk = b & 63;
    int lo    = slice * SLICE;
    const ushort_t* rel = rep + (size_t)(NCHUNK + chunk) * NTOT + lo;

    for (int i = threadIdx.x; i < SLICE; i += 256) {
        int n = lo + i;
        int r = (n < N_NODES) ? row_ofs[n] : 0;
        cur[i] = r + (int)rel[i];
    }
    __syncthreads();

    int q0 = chunk * QPC;
    int q1 = q0 + QPC;
    for (int q = q0 + threadIdx.x; q < q1; q += 256) {
        int4 s = src4[q];
        int4 d = dst4[q];
        unsigned a0 = (unsigned)(d.x - lo); if (a0 < SLICE) esrc[atomicAdd(&cur[a0], 1)] = s.x;
        unsigned a1 = (unsigned)(d.y - lo); if (a1 < SLICE) esrc[atomicAdd(&cur[a1], 1)] = s.y;
        unsigned a2 = (unsigned)(d.z - lo); if (a2 < SLICE) esrc[atomicAdd(&cur[a2], 1)] = s.z;
        unsigned a3 = (unsigned)(d.w - lo); if (a3 < SLICE) esrc[atomicAdd(&cur[a3], 1)] = s.w;
    }
}

// ---------------- z = bf16(out_norm * (feat @ Wc + bc)) via MFMA, LDS-B ----------------
// y-split = 2 (BN=64, 32KB B-panel): feat read only 2x (y=4 went HBM-bound, R14).
// LDS-B XOR-swizzled on lgkm counter; 2-deep A register pipeline. Fragments
// (m89): A m=lane&15, k=(lane>>4)*8+i; B n=lane&15 same k; D row=(lane>>4)*4+r,
// col=lane&15.
__global__ __launch_bounds__(256) void gemm_z(const float* __restrict__ feat,
                                              const ushort_t* __restrict__ Wcs,
                                              const float* __restrict__ bc,
                                              const float* __restrict__ out_norm,
                                              ushort_t* __restrict__ zb) {
    __shared__ ushort_t Bs[64 * IN_DIM];     // 32KB, 512B per col-row, swizzled
    int t    = threadIdx.x;
    int lane = t & 63;
    int wv   = t >> 6;
    int bm   = blockIdx.x * 64 + wv * 16;
    int bn0  = blockIdx.y * 64;
    int mrow = lane & 15;
    int kg   = lane >> 4;
    int gm   = bm + mrow;

    {
        const char* wsrc = (const char*)(Wcs + (size_t)bn0 * IN_DIM);
        char* bdst = (char*)Bs;
#pragma unroll
        for (int p = 0; p < 8; ++p) {
            int d  = p * 4096 + t * 16;
            int ds = d ^ (((d >> 9) & 7) << 4);
            *(int4*)(bdst + ds) = *(const int4*)(wsrc + d);
        }
    }
    __syncthreads();

    f32x4 acc[4];
#pragma unroll
    for (int nt = 0; nt < 4; ++nt) acc[nt] = (f32x4){0.f, 0.f, 0.f, 0.f};

    int boff[4];
#pragma unroll
    for (int nt = 0; nt < 4; ++nt) {
        int n = nt * 16 + mrow;
        boff[nt] = n * 512 + ((kg * 16) ^ ((n & 7) << 4));
    }
    const char* bsp = (const char*)Bs;

    bool valid = gm < N_NODES;
    const float* fp = feat + (size_t)(valid ? gm : 0) * IN_DIM + kg * 8;
    const float4 zf4 = make_float4(0.f, 0.f, 0.f, 0.f);

    float4 a0c = valid ? *(const float4*)(fp + 0) : zf4;
    float4 a1c = valid ? *(const float4*)(fp + 4) : zf4;
    float4 a0n = zf4, a1n = zf4;

#pragma unroll
    for (int kt = 0; kt < IN_DIM / 32; ++kt) {
        if (kt < IN_DIM / 32 - 1) {            // prefetch next kt (2-deep pipeline)
            a0n = valid ? *(const float4*)(fp + (kt + 1) * 32) : zf4;
            a1n = valid ? *(const float4*)(fp + (kt + 1) * 32 + 4) : zf4;
        }
        bf16x8 af;
        af[0] = (short)f2b(a0c.x); af[1] = (short)f2b(a0c.y);
        af[2] = (short)f2b(a0c.z); af[3] = (short)f2b(a0c.w);
        af[4] = (short)f2b(a1c.x); af[5] = (short)f2b(a1c.y);
        af[6] = (short)f2b(a1c.z); af[7] = (short)f2b(a1c.w);
#pragma unroll
        for (int nt = 0; nt < 4; ++nt) {
            bf16x8 bf = *(const bf16x8*)(bsp + (boff[nt] ^ (kt << 6)));
            acc[nt] = __builtin_amdgcn_mfma_f32_16x16x32_bf16(af, bf, acc[nt], 0, 0, 0);
        }
        a0c = a0n; a1c = a1n;
    }

    float on[4];
#pragma unroll
    for (int r = 0; r < 4; ++r) {
        int row = bm + kg * 4 + r;
        on[r] = (row < N_NODES) ? out_norm[row] : 0.f;
    }
#pragma unroll
    for (int nt = 0; nt < 4; ++nt) {
        int col = bn0 + nt * 16 + mrow;
        float bcv = bc[col];
#pragma unroll
        for (int r = 0; r < 4; ++r) {
            int row = bm + kg * 4 + r;
            if (row < N_NODES)
                zb[(size_t)row * OUT_DIM + col] = f2b(on[r] * (acc[nt][r] + bcv));
        }
    }
}

// -------- pull aggregate + fused in_norm/bias/leaky_relu: 4 nodes/wave, uint4 rows --------
// Block 0 also initializes out = b_cls (runs before readout's atomics; re-done
// every replay -> deterministic under graph replay; replaces the cls bias).
__global__ __launch_bounds__(256) void gather_kernel(const uint4* __restrict__ zb4,
                                                     const int* __restrict__ esrc,
                                                     const int* __restrict__ row_ofs,
                                                     const float* __restrict__ in_norm,
                                                     const float* __restrict__ b2,
                                                     uint4* __restrict__ hb4,
                                                     const float* __restrict__ b_cls,
                                                     float* __restrict__ out) {
    if (blockIdx.x == 0 && threadIdx.x < 2 * N_GRAPHS)
        out[threadIdx.x] = b_cls[threadIdx.x & 1];

    int n      = blockIdx.x * 16 + (threadIdx.x >> 4);   // grid*16 == N_NODES exactly
    int lane16 = threadIdx.x & 15;
    int e0 = row_ofs[n];
    int e1 = row_ofs[n + 1];
    float ac[8];
#pragma unroll
    for (int i = 0; i < 8; ++i) ac[i] = 0.f;

    int e = e0;
    for (; e + 8 <= e1; e += 8) {
        uint4 v[8];
#pragma unroll
        for (int u = 0; u < 8; ++u) v[u] = zb4[(size_t)esrc[e + u] * 16 + lane16];
#pragma unroll
        for (int u = 0; u < 8; ++u) {
            ac[0] += blo(v[u].x); ac[1] += bhi(v[u].x);
            ac[2] += blo(v[u].y); ac[3] += bhi(v[u].y);
            ac[4] += blo(v[u].z); ac[5] += bhi(v[u].z);
            ac[6] += blo(v[u].w); ac[7] += bhi(v[u].w);
        }
    }
    if (e + 4 <= e1) {
        uint4 v[4];
#pragma unroll
        for (int u = 0; u < 4; ++u) v[u] = zb4[(size_t)esrc[e + u] * 16 + lane16];
#pragma unroll
        for (int u = 0; u < 4; ++u) {
            ac[0] += blo(v[u].x); ac[1] += bhi(v[u].x);
            ac[2] += blo(v[u].y); ac[3] += bhi(v[u].y);
            ac[4] += blo(v[u].z); ac[5] += bhi(v[u].z);
            ac[6] += blo(v[u].w); ac[7] += bhi(v[u].w);
        }
        e += 4;
    }
    for (; e < e1; ++e) {
        uint4 v = zb4[(size_t)esrc[e] * 16 + lane16];
        ac[0] += blo(v.x); ac[1] += bhi(v.x);
        ac[2] += blo(v.y); ac[3] += bhi(v.y);
        ac[4] += blo(v.z); ac[5] += bhi(v.z);
        ac[6] += blo(v.w); ac[7] += bhi(v.w);
    }

    float inn = in_norm[n];
    float4 bA = *(const float4*)&b2[lane16 * 8];
    float4 bB = *(const float4*)&b2[lane16 * 8 + 4];
    float hv[8];
    hv[0] = fmaf(inn, ac[0], bA.x); hv[1] = fmaf(inn, ac[1], bA.y);
    hv[2] = fmaf(inn, ac[2], bA.z); hv[3] = fmaf(inn, ac[3], bA.w);
    hv[4] = fmaf(inn, ac[4], bB.x); hv[5] = fmaf(inn, ac[5], bB.y);
    hv[6] = fmaf(inn, ac[6], bB.z); hv[7] = fmaf(inn, ac[7], bB.w);
#pragma unroll
    for (int i = 0; i < 8; ++i) hv[i] = (hv[i] > 0.f) ? hv[i] : NEG_SLOPE * hv[i];
    uint4 o;
    o.x = (uint_t)f2b(hv[0]) | ((uint_t)f2b(hv[1]) << 16);
    o.y = (uint_t)f2b(hv[2]) | ((uint_t)f2b(hv[3]) << 16);
    o.z = (uint_t)f2b(hv[4]) | ((uint_t)f2b(hv[5]) << 16);
    o.w = (uint_t)f2b(hv[6]) | ((uint_t)f2b(hv[7]) << 16);
    hb4[(size_t)n * 16 + lane16] = o;
}

// ------- readout + classifier fused: per-segment partial dot with w_cls -------
// One wave per 64-node chunk; lane t owns cols {2t,2t+1}. At each graph-boundary
// flush, compute the 2-wide partial dot (acc . w_cls) via wave-reduce and do
// 2 atomics into out (replaces g accumulation + separate cls GEMV launch).
__global__ __launch_bounds__(64) void readout_kernel(const uint_t* __restrict__ hb2,
                                                     const int* __restrict__ gids,
                                                     const float* __restrict__ w_cls,
                                                     float* __restrict__ out) {
    int t    = threadIdx.x;                  // 0..63
    int n0   = blockIdx.x * RCHUNK;
    int nend = n0 + RCHUNK;
    if (nend > N_NODES) nend = N_NODES;
    float4 wv = *(const float4*)&w_cls[4 * t];   // cols {2t,2t+1} x classes {0,1}
    float acc0 = 0.f, acc1 = 0.f;
    int   cur = gids[n0];
    for (int n = n0; n < nend; ++n) {
        int gid = gids[n];
        if (gid != cur) {
            float p0 = acc0 * wv.x + acc1 * wv.z;
            float p1 = acc0 * wv.y + acc1 * wv.w;
#pragma unroll
            for (int off = 32; off > 0; off >>= 1) {
                p0 += __shfl_down(p0, off, 64);
                p1 += __shfl_down(p1, off, 64);
            }
            if (t == 0) {
                atomicAdd(&out[cur * 2 + 0], p0);
                atomicAdd(&out[cur * 2 + 1], p1);
            }
            acc0 = acc1 = 0.f;
            cur = gid;
        }
        uint_t v = hb2[(size_t)n * 64 + t];
        acc0 += blo(v);
        acc1 += bhi(v);
    }
    float p0 = acc0 * wv.x + acc1 * wv.z;
    float p1 = acc0 * wv.y + acc1 * wv.w;
#pragma unroll
    for (int off = 32; off > 0; off >>= 1) {
        p0 += __shfl_down(p0, off, 64);
        p1 += __shfl_down(p1, off, 64);
    }
    if (t == 0) {
        atomicAdd(&out[cur * 2 + 0], p0);
        atomicAdd(&out[cur * 2 + 1], p1);
    }
}

extern "C" void kernel_launch(void* const* d_in, const int* in_sizes, int n_in,
                              void* d_out, int out_size, void* d_ws, size_t ws_size,
                              hipStream_t stream) {
    const float* feat  = (const float*)d_in[0];
    const int*   src   = (const int*)d_in[1];
    const int*   dst   = (const int*)d_in[2];
    const int*   gids  = (const int*)d_in[3];
    const float* w_red = (const float*)d_in[4];
    const float* b_red = (const float*)d_in[5];
    const float* w_gcn = (const float*)d_in[6];
    const float* b_gcn = (const float*)d_in[7];
    const float* w_cls = (const float*)d_in[8];
    const float* b_cls = (const float*)d_in[9];
    float* out = (float*)d_out;

    // workspace layout (z/h regions sized as fp32 but used as bf16 -> half used)
    float* z        = (float*)d_ws;                       // 25.6MB region; zb uses 12.8
    float* h        = z + (size_t)N_NODES * OUT_DIM;      // 25.6MB region; hb uses 12.8
    float* out_norm = h + (size_t)N_NODES * OUT_DIM;      // 50000
    float* in_norm  = out_norm + N_NODES;                 // 50000
    int*   deg_in   = (int*)(in_norm + N_NODES);          // 50000 (compact)
    int*   row_ofs  = deg_in + N_NODES;                   // 50001
    int*   esrc     = row_ofs + N_NODES + 1;              // 800000
    int*   bsum     = esrc + N_EDGES;                     // NB_SCAN
    ushort_t* Wcs   = (ushort_t*)(bsum + NB_SCAN);        // 32768 bf16
    float* bc       = (float*)(Wcs + IN_DIM * OUT_DIM);   // 128

    ushort_t* zb = (ushort_t*)z;
    ushort_t* hb = (ushort_t*)h;

    // u16 per-chunk histograms rep[2][NCHUNK][NTOT] = 12.8MB ALIAS z region
    // (deg/norm/build all complete before gemm_z writes zb).
    ushort_t* rep = (ushort_t*)z;

    const float* w2 = w_gcn + 2 * OUT_DIM * OUT_DIM;      // layer 2 weights
    const float* b2 = b_gcn + 2 * OUT_DIM;                // layer 2 bias

    deg_kernel<<<2 * NSLICE * NCHUNK, 256, 0, stream>>>((const int4*)src, (const int4*)dst, rep);
    norm_kernel<<<NB_SCAN, 256, 0, stream>>>(rep, out_norm, in_norm, deg_in, bsum);
    fillwc_kernel<<<NB_SCAN + IN_DIM + 1, 256, 0, stream>>>(deg_in, bsum, row_ofs,
                                                            w_red, b_red, w2, Wcs, bc);
    build_kernel<<<NSLICE * NCHUNK, 256, 0, stream>>>((const int4*)src, (const int4*)dst,
                                                      row_ofs, rep, esrc);
    gemm_z<<<dim3((N_NODES + 63) / 64, 2), 256, 0, stream>>>(feat, Wcs, bc, out_norm, zb);
    gather_kernel<<<N_NODES / 16, 256, 0, stream>>>((const uint4*)zb, esrc, row_ofs,
                                                    in_norm, b2, (uint4*)hb, b_cls, out);
    readout_kernel<<<(N_NODES + RCHUNK - 1) / RCHUNK, 64, 0, stream>>>((const uint_t*)hb,
                                                                       gids, w_cls, out);
}

// Round 17
// 140.864 us; speedup vs baseline: 1.1532x; 1.0429x over previous
//
#include <hip/hip_runtime.h>

#define N_NODES 50000
#define N_EDGES 800000
#define N_GRAPHS 128
#define IN_DIM 256
#define OUT_DIM 128
#define NEG_SLOPE 0.01f

#define NB_SCAN ((N_NODES + 255) / 256)   // 196 blocks for the scan

#define NSLICE 4
#define SLICE 12544                        // 4*12544 = 50176 >= N_NODES
#define NTOT (NSLICE * SLICE)              // 50176
#define NCHUNK 64
#define NE4 (N_EDGES / 4)                  // 200000 int4 quads
#define QPC (NE4 / NCHUNK)                 // 3125 quads per chunk

typedef __attribute__((ext_vector_type(8))) short bf16x8;
typedef __attribute__((ext_vector_type(4))) float f32x4;
typedef unsigned short ushort_t;
typedef unsigned int uint_t;

__device__ inline ushort_t f2b(float f) {          // fp32 -> bf16 bits, RNE
    union { float f; unsigned u; } c{f};
    unsigned r = c.u + 0x7FFFu + ((c.u >> 16) & 1u);
    return (ushort_t)(r >> 16);
}
__device__ inline float blo(uint_t v) {            // low bf16 of packed pair
    union { unsigned u; float f; } c{v << 16};
    return c.f;
}
__device__ inline float bhi(uint_t v) {            // high bf16 of packed pair
    union { unsigned u; float f; } c{v & 0xFFFF0000u};
    return c.f;
}

// ------- degree histograms: packed-u16 LDS bins (25KB), zero global atomics -------
__global__ __launch_bounds__(256) void deg_kernel(const int4* __restrict__ src4,
                                                  const int4* __restrict__ dst4,
                                                  ushort_t* __restrict__ rep) {
    __shared__ uint_t bins[SLICE / 2];   // 25KB -> 6 blocks/CU
    int b     = blockIdx.x;
    int hist  = b >> 8;                  // 0: src (out-deg), 1: dst (in-deg)
    int rem   = b & 255;
    int slice = rem >> 6;
    int chunk = rem & 63;
    const int4* ea = hist ? dst4 : src4;
    int lo = slice * SLICE;

    for (int i = threadIdx.x; i < SLICE / 2; i += 256) bins[i] = 0;
    __syncthreads();

    int q0 = chunk * QPC;
    int q1 = q0 + QPC;
    for (int q = q0 + threadIdx.x; q < q1; q += 256) {
        int4 e = ea[q];
        unsigned a0 = (unsigned)(e.x - lo);
        if (a0 < SLICE) atomicAdd(&bins[a0 >> 1], 1u << ((a0 & 1) << 4));
        unsigned a1 = (unsigned)(e.y - lo);
        if (a1 < SLICE) atomicAdd(&bins[a1 >> 1], 1u << ((a1 & 1) << 4));
        unsigned a2 = (unsigned)(e.z - lo);
        if (a2 < SLICE) atomicAdd(&bins[a2 >> 1], 1u << ((a2 & 1) << 4));
        unsigned a3 = (unsigned)(e.w - lo);
        if (a3 < SLICE) atomicAdd(&bins[a3 >> 1], 1u << ((a3 & 1) << 4));
    }
    __syncthreads();

    uint_t* rp32 = (uint_t*)(rep + (size_t)(hist * NCHUNK + chunk) * NTOT + lo);
    for (int i = threadIdx.x; i < SLICE / 2; i += 256)
        rp32[i] = bins[i];
}

// ---- reduce replicas -> norms + deg_in; in-place chunk-prefix scan; fused block sums ----
__global__ __launch_bounds__(256) void norm_kernel(ushort_t* __restrict__ rep,
                                                   float* __restrict__ out_norm,
                                                   float* __restrict__ in_norm,
                                                   int* __restrict__ deg_in_tot,
                                                   int* __restrict__ bsum) {
    __shared__ int red[256];
    int t = threadIdx.x;
    int i = blockIdx.x * 256 + t;
    int si_keep = 0;
    if (i < N_NODES) {
        int so = 0;
#pragma unroll
        for (int c = 0; c < NCHUNK; ++c) so += rep[(size_t)c * NTOT + i];
        int si = 0;
#pragma unroll
        for (int c = 0; c < NCHUNK; ++c) {       // exclusive scan, in place
            size_t off = (size_t)(NCHUNK + c) * NTOT + i;
            int v = rep[off];
            rep[off] = (ushort_t)si;
            si += v;
        }
        deg_in_tot[i] = si;
        si_keep = si;
        int dq = so > 1 ? so : 1;
        int di = si > 1 ? si : 1;
        out_norm[i] = rsqrtf((float)dq);
        in_norm[i]  = rsqrtf((float)di);
    }
    red[t] = si_keep;
    __syncthreads();
    for (int off = 128; off > 0; off >>= 1) {
        if (t < off) red[t] += red[t + off];
        __syncthreads();
    }
    if (t == 0) bsum[blockIdx.x] = red[0];
}

// ---- merged fill + wc: blocks 0..195 build row_ofs; blocks 196..452 fold weights ----
// Block NB_SCAN also initializes out = b_cls (ordered before gather's atomics).
__global__ __launch_bounds__(256) void fillwc_kernel(const int* __restrict__ deg_in,
                                                     const int* __restrict__ bsum,
                                                     int* __restrict__ row_ofs,
                                                     const float* __restrict__ w_red,
                                                     const float* __restrict__ b_red,
                                                     const float* __restrict__ w2,
                                                     ushort_t* __restrict__ Wcs,
                                                     float* __restrict__ bc,
                                                     const float* __restrict__ b_cls,
                                                     float* __restrict__ out) {
    int t   = threadIdx.x;
    int bid = blockIdx.x;

    if (bid < NB_SCAN) {
        // ---------- fill part ----------
        __shared__ int sh[256];
        // phase A: scan block sums
        int v = (t < NB_SCAN) ? bsum[t] : 0;
        sh[t] = v;
        __syncthreads();
        for (int off = 1; off < 256; off <<= 1) {
            int a = sh[t];
            int b = (t >= off) ? sh[t - off] : 0;
            __syncthreads();
            sh[t] = a + b;
            __syncthreads();
        }
        int bofs  = sh[bid] - bsum[bid];          // exclusive prefix of this block
        int total = sh[NB_SCAN - 1];
        __syncthreads();

        // phase B: block-local scan of degrees
        int idx = bid * 256 + t;
        int dv  = (idx < N_NODES) ? deg_in[idx] : 0;
        sh[t] = dv;
        __syncthreads();
        for (int off = 1; off < 256; off <<= 1) {
            int a = sh[t];
            int b = (t >= off) ? sh[t - off] : 0;
            __syncthreads();
            sh[t] = a + b;
            __syncthreads();
        }
        if (idx < N_NODES) row_ofs[idx] = bofs + sh[t] - dv;
        if (bid == 0 && t == 0) row_ofs[N_NODES] = total;   // = N_EDGES
    } else {
        if (bid == NB_SCAN) out[t] = b_cls[t & 1];          // 256 = 2*N_GRAPHS
        if (t < OUT_DIM) {
            // ---------- wc part: Wcs[n][k] = bf16(sum_c w_red[k][c] w2[c][n]) ----------
            int i = bid - NB_SCAN;   // k: 0..256 (i==IN_DIM computes bc)
            int j = t;               // n: 0..127
            const float* vin = (i < IN_DIM) ? (w_red + (size_t)i * OUT_DIM) : b_red;
            float s = 0.f;
            for (int k = 0; k < OUT_DIM; ++k) s = fmaf(vin[k], w2[k * OUT_DIM + j], s);
            if (i < IN_DIM) Wcs[(size_t)j * IN_DIM + i] = f2b(s);   // transposed, bf16
            else            bc[j] = s;
        }
    }
}

// ------- chunked bucket fill: LDS cursors, zero global atomics; esrc as u16 -------
__global__ __launch_bounds__(256) void build_kernel(const int4* __restrict__ src4,
                                                    const int4* __restrict__ dst4,
                                                    const int* __restrict__ row_ofs,
                                                    const ushort_t* __restrict__ rep,
                                                    ushort_t* __restrict__ esrc) {
    __shared__ int cur[SLICE];
    int b     = blockIdx.x;
    int slice = b >> 6;
    int chunk = b & 63;
    int lo    = slice * SLICE;
    const ushort_t* rel = rep + (size_t)(NCHUNK + chunk) * NTOT + lo;

    for (int i = threadIdx.x; i < SLICE; i += 256) {
        int n = lo + i;
        int r = (n < N_NODES) ? row_ofs[n] : 0;
        cur[i] = r + (int)rel[i];
    }
    __syncthreads();

    int q0 = chunk * QPC;
    int q1 = q0 + QPC;
    for (int q = q0 + threadIdx.x; q < q1; q += 256) {
        int4 s = src4[q];
        int4 d = dst4[q];
        unsigned a0 = (unsigned)(d.x - lo); if (a0 < SLICE) esrc[atomicAdd(&cur[a0], 1)] = (ushort_t)s.x;
        unsigned a1 = (unsigned)(d.y - lo); if (a1 < SLICE) esrc[atomicAdd(&cur[a1], 1)] = (ushort_t)s.y;
        unsigned a2 = (unsigned)(d.z - lo); if (a2 < SLICE) esrc[atomicAdd(&cur[a2], 1)] = (ushort_t)s.z;
        unsigned a3 = (unsigned)(d.w - lo); if (a3 < SLICE) esrc[atomicAdd(&cur[a3], 1)] = (ushort_t)s.w;
    }
}

// ---------------- z = bf16(out_norm * (feat @ Wc + bc)) via MFMA, LDS-B ----------------
// y-split = 2 (BN=64, 32KB B-panel): feat read only 2x (y=4 went HBM-bound, R14).
// LDS-B XOR-swizzled on lgkm counter; 2-deep A register pipeline. Fragments
// (m89): A m=lane&15, k=(lane>>4)*8+i; B n=lane&15 same k; D row=(lane>>4)*4+r,
// col=lane&15.
__global__ __launch_bounds__(256) void gemm_z(const float* __restrict__ feat,
                                              const ushort_t* __restrict__ Wcs,
                                              const float* __restrict__ bc,
                                              const float* __restrict__ out_norm,
                                              ushort_t* __restrict__ zb) {
    __shared__ ushort_t Bs[64 * IN_DIM];     // 32KB, 512B per col-row, swizzled
    int t    = threadIdx.x;
    int lane = t & 63;
    int wv   = t >> 6;
    int bm   = blockIdx.x * 64 + wv * 16;
    int bn0  = blockIdx.y * 64;
    int mrow = lane & 15;
    int kg   = lane >> 4;
    int gm   = bm + mrow;

    {
        const char* wsrc = (const char*)(Wcs + (size_t)bn0 * IN_DIM);
        char* bdst = (char*)Bs;
#pragma unroll
        for (int p = 0; p < 8; ++p) {
            int d  = p * 4096 + t * 16;
            int ds = d ^ (((d >> 9) & 7) << 4);
            *(int4*)(bdst + ds) = *(const int4*)(wsrc + d);
        }
    }
    __syncthreads();

    f32x4 acc[4];
#pragma unroll
    for (int nt = 0; nt < 4; ++nt) acc[nt] = (f32x4){0.f, 0.f, 0.f, 0.f};

    int boff[4];
#pragma unroll
    for (int nt = 0; nt < 4; ++nt) {
        int n = nt * 16 + mrow;
        boff[nt] = n * 512 + ((kg * 16) ^ ((n & 7) << 4));
    }
    const char* bsp = (const char*)Bs;

    bool valid = gm < N_NODES;
    const float* fp = feat + (size_t)(valid ? gm : 0) * IN_DIM + kg * 8;
    const float4 zf4 = make_float4(0.f, 0.f, 0.f, 0.f);

    float4 a0c = valid ? *(const float4*)(fp + 0) : zf4;
    float4 a1c = valid ? *(const float4*)(fp + 4) : zf4;
    float4 a0n = zf4, a1n = zf4;

#pragma unroll
    for (int kt = 0; kt < IN_DIM / 32; ++kt) {
        if (kt < IN_DIM / 32 - 1) {            // prefetch next kt (2-deep pipeline)
            a0n = valid ? *(const float4*)(fp + (kt + 1) * 32) : zf4;
            a1n = valid ? *(const float4*)(fp + (kt + 1) * 32 + 4) : zf4;
        }
        bf16x8 af;
        af[0] = (short)f2b(a0c.x); af[1] = (short)f2b(a0c.y);
        af[2] = (short)f2b(a0c.z); af[3] = (short)f2b(a0c.w);
        af[4] = (short)f2b(a1c.x); af[5] = (short)f2b(a1c.y);
        af[6] = (short)f2b(a1c.z); af[7] = (short)f2b(a1c.w);
#pragma unroll
        for (int nt = 0; nt < 4; ++nt) {
            bf16x8 bf = *(const bf16x8*)(bsp + (boff[nt] ^ (kt << 6)));
            acc[nt] = __builtin_amdgcn_mfma_f32_16x16x32_bf16(af, bf, acc[nt], 0, 0, 0);
        }
        a0c = a0n; a1c = a1n;
    }

    float on[4];
#pragma unroll
    for (int r = 0; r < 4; ++r) {
        int row = bm + kg * 4 + r;
        on[r] = (row < N_NODES) ? out_norm[row] : 0.f;
    }
#pragma unroll
    for (int nt = 0; nt < 4; ++nt) {
        int col = bn0 + nt * 16 + mrow;
        float bcv = bc[col];
#pragma unroll
        for (int r = 0; r < 4; ++r) {
            int row = bm + kg * 4 + r;
            if (row < N_NODES)
                zb[(size_t)row * OUT_DIM + col] = f2b(on[r] * (acc[nt][r] + bcv));
        }
    }
}

// ---- gather + norm/bias/lrelu + CLASSIFIER fused: 4 nodes/wave, uint4 rows ----
// Quarter-wave (16 lanes) per node; per-node fp32 hv dotted with w_cls in-register,
// shfl-reduced across the 16 lanes, block-level segment-merge (gids sorted) ->
// 1-2 atomicAdds into out per block. hb buffer and readout kernel eliminated.
__global__ __launch_bounds__(256) void gather_kernel(const uint4* __restrict__ zb4,
                                                     const ushort_t* __restrict__ esrc,
                                                     const int* __restrict__ row_ofs,
                                                     const float* __restrict__ in_norm,
                                                     const float* __restrict__ b2,
                                                     const int* __restrict__ gids,
                                                     const float* __restrict__ w_cls,
                                                     float* __restrict__ out) {
    __shared__ int   pg[16];
    __shared__ float pp0[16], pp1[16];

    int n      = blockIdx.x * 16 + (threadIdx.x >> 4);   // grid*16 == N_NODES exactly
    int lane16 = threadIdx.x & 15;
    int e0 = row_ofs[n];
    int e1 = row_ofs[n + 1];
    float ac[8];
#pragma unroll
    for (int i = 0; i < 8; ++i) ac[i] = 0.f;

    int e = e0;
    for (; e + 8 <= e1; e += 8) {
        uint4 v[8];
#pragma unroll
        for (int u = 0; u < 8; ++u) v[u] = zb4[(size_t)esrc[e + u] * 16 + lane16];
#pragma unroll
        for (int u = 0; u < 8; ++u) {
            ac[0] += blo(v[u].x); ac[1] += bhi(v[u].x);
            ac[2] += blo(v[u].y); ac[3] += bhi(v[u].y);
            ac[4] += blo(v[u].z); ac[5] += bhi(v[u].z);
            ac[6] += blo(v[u].w); ac[7] += bhi(v[u].w);
        }
    }
    if (e + 4 <= e1) {
        uint4 v[4];
#pragma unroll
        for (int u = 0; u < 4; ++u) v[u] = zb4[(size_t)esrc[e + u] * 16 + lane16];
#pragma unroll
        for (int u = 0; u < 4; ++u) {
            ac[0] += blo(v[u].x); ac[1] += bhi(v[u].x);
            ac[2] += blo(v[u].y); ac[3] += bhi(v[u].y);
            ac[4] += blo(v[u].z); ac[5] += bhi(v[u].z);
            ac[6] += blo(v[u].w); ac[7] += bhi(v[u].w);
        }
        e += 4;
    }
    for (; e < e1; ++e) {
        uint4 v = zb4[(size_t)esrc[e] * 16 + lane16];
        ac[0] += blo(v.x); ac[1] += bhi(v.x);
        ac[2] += blo(v.y); ac[3] += bhi(v.y);
        ac[4] += blo(v.z); ac[5] += bhi(v.z);
        ac[6] += blo(v.w); ac[7] += bhi(v.w);
    }

    float inn = in_norm[n];
    float4 bA = *(const float4*)&b2[lane16 * 8];
    float4 bB = *(const float4*)&b2[lane16 * 8 + 4];
    float hv[8];
    hv[0] = fmaf(inn, ac[0], bA.x); hv[1] = fmaf(inn, ac[1], bA.y);
    hv[2] = fmaf(inn, ac[2], bA.z); hv[3] = fmaf(inn, ac[3], bA.w);
    hv[4] = fmaf(inn, ac[4], bB.x); hv[5] = fmaf(inn, ac[5], bB.y);
    hv[6] = fmaf(inn, ac[6], bB.z); hv[7] = fmaf(inn, ac[7], bB.w);
#pragma unroll
    for (int i = 0; i < 8; ++i) hv[i] = (hv[i] > 0.f) ? hv[i] : NEG_SLOPE * hv[i];

    // classifier partial dot: lane16 owns cols lane16*8 .. +7
    float p0 = 0.f, p1 = 0.f;
#pragma unroll
    for (int k = 0; k < 4; ++k) {
        float4 q = ((const float4*)w_cls)[lane16 * 4 + k];   // cols {8l+2k, 8l+2k+1} x {c0,c1}
        p0 += hv[2 * k] * q.x + hv[2 * k + 1] * q.z;
        p1 += hv[2 * k] * q.y + hv[2 * k + 1] * q.w;
    }
#pragma unroll
    for (int off = 8; off > 0; off >>= 1) {
        p0 += __shfl_down(p0, off, 16);
        p1 += __shfl_down(p1, off, 16);
    }
    if (lane16 == 0) {
        int qw = threadIdx.x >> 4;
        pg[qw]  = gids[n];
        pp0[qw] = p0;
        pp1[qw] = p1;
    }
    __syncthreads();
    if (threadIdx.x == 0) {
        int cg = pg[0];
        float a0 = 0.f, a1 = 0.f;
        for (int j = 0; j < 16; ++j) {
            if (pg[j] != cg) {
                atomicAdd(&out[cg * 2 + 0], a0);
                atomicAdd(&out[cg * 2 + 1], a1);
                cg = pg[j];
                a0 = a1 = 0.f;
            }
            a0 += pp0[j];
            a1 += pp1[j];
        }
        atomicAdd(&out[cg * 2 + 0], a0);
        atomicAdd(&out[cg * 2 + 1], a1);
    }
}

extern "C" void kernel_launch(void* const* d_in, const int* in_sizes, int n_in,
                              void* d_out, int out_size, void* d_ws, size_t ws_size,
                              hipStream_t stream) {
    const float* feat  = (const float*)d_in[0];
    const int*   src   = (const int*)d_in[1];
    const int*   dst   = (const int*)d_in[2];
    const int*   gids  = (const int*)d_in[3];
    const float* w_red = (const float*)d_in[4];
    const float* b_red = (const float*)d_in[5];
    const float* w_gcn = (const float*)d_in[6];
    const float* b_gcn = (const float*)d_in[7];
    const float* w_cls = (const float*)d_in[8];
    const float* b_cls = (const float*)d_in[9];
    float* out = (float*)d_out;

    // workspace layout
    float* z        = (float*)d_ws;                       // 25.6MB region; zb uses 12.8
    float* out_norm = z + (size_t)N_NODES * OUT_DIM;      // 50000
    float* in_norm  = out_norm + N_NODES;                 // 50000
    int*   deg_in   = (int*)(in_norm + N_NODES);          // 50000 (compact)
    int*   row_ofs  = deg_in + N_NODES;                   // 50001
    ushort_t* esrc  = (ushort_t*)(row_ofs + N_NODES + 1); // 800000 u16
    int*   bsum     = (int*)(esrc + N_EDGES);             // NB_SCAN
    ushort_t* Wcs   = (ushort_t*)(bsum + NB_SCAN);        // 32768 bf16
    float* bc       = (float*)(Wcs + IN_DIM * OUT_DIM);   // 128

    ushort_t* zb = (ushort_t*)z;

    // u16 per-chunk histograms rep[2][NCHUNK][NTOT] = 12.85MB ALIAS z region
    // (deg/norm/build all complete before gemm_z writes zb).
    ushort_t* rep = (ushort_t*)z;

    const float* w2 = w_gcn + 2 * OUT_DIM * OUT_DIM;      // layer 2 weights
    const float* b2 = b_gcn + 2 * OUT_DIM;                // layer 2 bias

    deg_kernel<<<2 * NSLICE * NCHUNK, 256, 0, stream>>>((const int4*)src, (const int4*)dst, rep);
    norm_kernel<<<NB_SCAN, 256, 0, stream>>>(rep, out_norm, in_norm, deg_in, bsum);
    fillwc_kernel<<<NB_SCAN + IN_DIM + 1, 256, 0, stream>>>(deg_in, bsum, row_ofs,
                                                            w_red, b_red, w2, Wcs, bc,
                                                            b_cls, out);
    build_kernel<<<NSLICE * NCHUNK, 256, 0, stream>>>((const int4*)src, (const int4*)dst,
                                                      row_ofs, rep, esrc);
    gemm_z<<<dim3((N_NODES + 63) / 64, 2), 256, 0, stream>>>(feat, Wcs, bc, out_norm, zb);
    gather_kernel<<<N_NODES / 16, 256, 0, stream>>>((const uint4*)zb, esrc, row_ofs,
                                                    in_norm, b2, gids, w_cls, out);
}